// Round 8
// baseline (168.643 us; speedup 1.0000x reference)
//
#include <hip/hip_runtime.h>
#include <hip/hip_bf16.h>
#include <cmath>

#define DIM 128
#define HEADS 8
#define NBATCH 2
#define NQ 6400   /* 80*80 */
#define NKV 1600  /* 40*40 */
#define NC 50     /* kv chunks of 32 */
#define BN_EPS 1e-5f
#define LOG2E 1.4426950408889634f

typedef __bf16 bf16_t;
typedef __attribute__((ext_vector_type(8))) __bf16 bf16x8;
typedef __attribute__((ext_vector_type(16))) float f32x16;

union BF8U { bf16x8 v; unsigned u[4]; };

// pack two f32 -> packed bf16 (a->lo, b->hi); lowers to v_cvt_pk_bf16_f32 (RNE)
__device__ inline unsigned packbf2(float a, float b) {
  union { __hip_bfloat162 v; unsigned u; } r;
  r.v = __float22bfloat162_rn(make_float2(a, b));
  return r.u;
}

__device__ inline unsigned short f2bf(float v) {
  unsigned u = __float_as_uint(v);
  return (unsigned short)((u + 0x7FFFu + ((u >> 16) & 1u)) >> 16);
}

// build bf16x8 B-fragment from 8 consecutive f32 weights (in-register cast)
__device__ inline bf16x8 ldw8(const float* __restrict__ p) {
  float4 w0 = *(const float4*)p;
  float4 w1 = *(const float4*)(p + 4);
  BF8U r;
  r.u[0] = packbf2(w0.x, w0.y);
  r.u[1] = packbf2(w0.z, w0.w);
  r.u[2] = packbf2(w1.x, w1.y);
  r.u[3] = packbf2(w1.z, w1.w);
  return r.v;
}

// ---------------------------------------------------------------------------
// Fused q + sr GEMM, reading A straight from x (no staging buffers).
// Block 256 = 4 waves; wave w owns o-tile w*32.
// blocks [0,200):   q tile: A[s][c] = x[b][c][s] (8 coalesced scalar f32/step)
//                   -> Qb bf16 token-major, value *SCALE*log2e, +bias
// blocks [200,250): sr tile: A[m][c4] = x[b][c4>>2][2i+(c4>>1&1)][2j+(c4&1)]
//                   (im2col offsets are unroll-time constants)
//                   -> BN(eval)+ReLU -> xkvb bf16 token-major
// Weights cast f32->bf16 in-register. C/D: col o=lane&31, row s=(r&3)+8(r>>2)+4hf.
// ---------------------------------------------------------------------------
__global__ __launch_bounds__(256) void mgemm_qsr(
    const float* __restrict__ x,
    const float* __restrict__ q_w, const float* __restrict__ q_b,
    const float* __restrict__ sr_w, const float* __restrict__ sr_b,
    const float* __restrict__ bng, const float* __restrict__ bnb,
    const float* __restrict__ bnm, const float* __restrict__ bnv,
    unsigned short* __restrict__ Qb, unsigned short* __restrict__ xkvb,
    float sl)
{
  int t = threadIdx.x;
  int ln = t & 31, hf = (t >> 5) & 1, wid = t >> 6;
  int b = blockIdx.y;
  int o = wid * 32 + ln;
  f32x16 acc = {};

  if (blockIdx.x < 200) {            // ---- q part (C = 128) ----
    int s0 = blockIdx.x * 32;
    const float* ab = x + (size_t)b * DIM * NQ + s0 + ln;   // + c*6400
    const float* brow = q_w + (size_t)o * 128 + hf * 8;
#pragma unroll
    for (int c0 = 0; c0 < 128; c0 += 16) {
      BF8U af;
#pragma unroll
      for (int jj = 0; jj < 4; ++jj)
        af.u[jj] = packbf2(ab[(size_t)(c0 + hf * 8 + 2 * jj) * NQ],
                           ab[(size_t)(c0 + hf * 8 + 2 * jj + 1) * NQ]);
      acc = __builtin_amdgcn_mfma_f32_32x32x16_bf16(af.v, ldw8(&brow[c0]), acc, 0, 0, 0);
    }
    float bv = q_b[o];
#pragma unroll
    for (int g = 0; g < 4; ++g)
#pragma unroll
      for (int j = 0; j < 4; ++j) {
        int s = s0 + 8 * g + 4 * hf + j;
        Qb[((size_t)b * NQ + s) * DIM + o] = f2bf((acc[4 * g + j] + bv) * sl);
      }
  } else {                           // ---- sr part (C = 512, im2col) ----
    int s0 = (blockIdx.x - 200) * 32;
    int m = s0 + ln;
    int i = m / 40, jp = m % 40;
    const float* ab = x + (size_t)b * DIM * NQ + i * 160 + 2 * jp; // +c*6400+ky*80+kx
    const float* brow = sr_w + (size_t)o * 512 + hf * 8;
#pragma unroll 4
    for (int c0 = 0; c0 < 512; c0 += 16) {
      BF8U af;
#pragma unroll
      for (int jj = 0; jj < 4; ++jj) {
        int ca = c0 + hf * 8 + 2 * jj, cb = ca + 1;
        float va_ = ab[(size_t)(ca >> 2) * NQ + ((ca >> 1) & 1) * 80 + (ca & 1)];
        float vb_ = ab[(size_t)(cb >> 2) * NQ + ((cb >> 1) & 1) * 80 + (cb & 1)];
        af.u[jj] = packbf2(va_, vb_);
      }
      acc = __builtin_amdgcn_mfma_f32_32x32x16_bf16(af.v, ldw8(&brow[c0]), acc, 0, 0, 0);
    }
    float bv = sr_b[o];
    float inv = bng[o] / sqrtf(bnv[o] + BN_EPS);
    float b2 = bnb[o] - bnm[o] * inv;
#pragma unroll
    for (int g = 0; g < 4; ++g)
#pragma unroll
      for (int j = 0; j < 4; ++j) {
        int s = s0 + 8 * g + 4 * hf + j;
        float v = fmaxf((acc[4 * g + j] + bv) * inv + b2, 0.f);
        xkvb[((size_t)b * NKV + s) * DIM + o] = f2bf(v);
      }
  }
}

// ---------------------------------------------------------------------------
// Fused k + v GEMM over xkvb (C=128). blockIdx.z: 0 = k, 1 = v.
// Weights cast in-register. Fragment-major epilogues (attention-coalesced):
// k -> Kp[(b*8+h)*50+chunk][s_local*16+d]
// v -> Vp[(b*8+h)*50+chunk][va:512 | vb:512] (kv-permuted identity w/ S-layout)
// v-branch also fills the softmax-denominator slots (lane16 rows = 1.0).
// ---------------------------------------------------------------------------
__global__ __launch_bounds__(256) void mgemm_kv(
    const bf16_t* __restrict__ xkvb,
    const float* __restrict__ k_w, const float* __restrict__ k_b,
    const float* __restrict__ v_w, const float* __restrict__ v_b,
    unsigned short* __restrict__ Kp, unsigned short* __restrict__ Vp)
{
  int t = threadIdx.x;
  int ln = t & 31, hf = (t >> 5) & 1, wid = t >> 6;
  int b = blockIdx.y;
  int isv = blockIdx.z;
  int s0 = blockIdx.x * 32;
  const float* W = isv ? v_w : k_w;
  int o = wid * 32 + ln;

  const bf16_t* arow = &xkvb[((size_t)b * NKV + s0 + ln) * DIM + hf * 8];
  const float* brow = W + (size_t)o * DIM + hf * 8;
  f32x16 acc = {};
#pragma unroll
  for (int c0 = 0; c0 < 128; c0 += 16) {
    bf16x8 af = *(const bf16x8*)&arow[c0];
    acc = __builtin_amdgcn_mfma_f32_32x32x16_bf16(af, ldw8(&brow[c0]), acc, 0, 0, 0);
  }

  int hloc = o >> 4, d = o & 15;
  if (isv) {
    float bv = v_b[o];
    size_t CB = (((size_t)b * HEADS + hloc) * NC + (s0 >> 5)) * 1024;
    uint4 w0, w1;
    w0.x = packbf2(acc[0] + bv, acc[1] + bv);
    w0.y = packbf2(acc[2] + bv, acc[3] + bv);
    w0.z = packbf2(acc[4] + bv, acc[5] + bv);
    w0.w = packbf2(acc[6] + bv, acc[7] + bv);
    w1.x = packbf2(acc[8] + bv, acc[9] + bv);
    w1.y = packbf2(acc[10] + bv, acc[11] + bv);
    w1.z = packbf2(acc[12] + bv, acc[13] + bv);
    w1.w = packbf2(acc[14] + bv, acc[15] + bv);
    *(uint4*)&Vp[CB + d * 16 + hf * 8] = w0;         // va block
    *(uint4*)&Vp[CB + 512 + d * 16 + hf * 8] = w1;   // vb block
    // denominator fill: lane-16 rows of both blocks = 1.0 bf16
    {
      int h2 = t >> 5, pos = t & 31;                 // 256 threads = 8h x 32pos
      size_t CB2 = (((size_t)b * HEADS + h2) * NC + (s0 >> 5)) * 1024;
      Vp[CB2 + 256 + ((pos & 16) ? 512 : 0) + (pos & 15)] = 0x3F80;
    }
  } else {
    float bv = k_b[o];
    size_t CB = (((size_t)b * HEADS + hloc) * NC + (s0 >> 5)) * 512;
#pragma unroll
    for (int g = 0; g < 4; ++g)
#pragma unroll
      for (int j = 0; j < 4; ++j) {
        int sl2 = 8 * g + 4 * hf + j;                // s_local row
        Kp[CB + sl2 * 16 + d] = f2bf(acc[4 * g + j] + bv);
      }
  }
}

// ---------------------------------------------------------------------------
// MFMA attention, kv-split = nsplit (2 or 4), fragment-major K/V.
// One wave = 32 q x one kv-range of one (b,h). 12800 waves at nsplit=4
// (12.5/SIMD) — TLP hides the L2 latency; no explicit prefetch (keeps
// VGPR <= 64 for 8 waves/EU via __launch_bounds__(256,8)).
// grid (50, 8, 2*nsplit): z = b + 2*quarter. block 256 (4 independent q-tiles).
// ---------------------------------------------------------------------------
__global__ __launch_bounds__(256, 8) void attn_split(
    const bf16_t* __restrict__ Qb, const bf16_t* __restrict__ Kp,
    const bf16_t* __restrict__ Vp, unsigned short* __restrict__ Pb,
    float* __restrict__ Lsum, int nsplit)
{
  const int t = threadIdx.x;
  const int ln = t & 31, hf = (t >> 5) & 1, wid = t >> 6;
  const int h = blockIdx.y;
  const int b = blockIdx.z & 1, quarter = blockIdx.z >> 1;
  const int q0 = blockIdx.x * 128 + wid * 32;
  const int base = NC / nsplit, rem = NC % nsplit;
  const int kcnt = base + (quarter < rem ? 1 : 0);
  const int kstart = quarter * base + (quarter < rem ? quarter : rem);
  const int slice = quarter * 2 + b;

  bf16x8 qf = *(const bf16x8*)&Qb[((size_t)b * NQ + q0 + ln) * DIM + h * 16 + hf * 8];
  const int bh = b * HEADS + h;
  const bf16_t* kc = &Kp[((size_t)bh * NC + kstart) * 512 + ln * 16 + hf * 8];
  const bf16_t* vc = &Vp[((size_t)bh * NC + kstart) * 1024 + ln * 16 + hf * 8];

  f32x16 acc = {};
  const f32x16 zero = {};

  for (int c = 0; c < kcnt; ++c) {
    bf16x8 kf = *(const bf16x8*)kc;
    bf16x8 va = *(const bf16x8*)vc;
    bf16x8 vb = *(const bf16x8*)(vc + 512);

    f32x16 S = __builtin_amdgcn_mfma_f32_32x32x16_bf16(kf, qf, zero, 0, 0, 0);

    BF8U f0, f1;
#pragma unroll
    for (int i = 0; i < 4; ++i) {
      f0.u[i] = packbf2(__builtin_amdgcn_exp2f(S[2 * i]),
                        __builtin_amdgcn_exp2f(S[2 * i + 1]));
      f1.u[i] = packbf2(__builtin_amdgcn_exp2f(S[8 + 2 * i]),
                        __builtin_amdgcn_exp2f(S[9 + 2 * i]));
    }

    acc = __builtin_amdgcn_mfma_f32_32x32x16_bf16(va, f0.v, acc, 0, 0, 0);
    acc = __builtin_amdgcn_mfma_f32_32x32x16_bf16(vb, f1.v, acc, 0, 0, 0);
    kc += 512; vc += 1024;
  }

  // acc: col q = ln, row d = (r&3)+8*(r>>2)+4*hf. Row16 (denom) = acc[8]@hf0.
  unsigned short* prow =
      &Pb[(size_t)slice * (NQ * DIM) + (size_t)(q0 + ln) * DIM + h * 16 + 4 * hf];
  uint2 w0, w1;
  w0.x = packbf2(acc[0], acc[1]); w0.y = packbf2(acc[2], acc[3]);
  w1.x = packbf2(acc[4], acc[5]); w1.y = packbf2(acc[6], acc[7]);
  *(uint2*)&prow[0] = w0;
  *(uint2*)&prow[8] = w1;
  if (!hf)
    Lsum[(size_t)slice * (HEADS * NQ) + (size_t)h * NQ + q0 + ln] = acc[8];
}

// ---------------------------------------------------------------------------
// proj_comb: fused combine (nsplit partials) + reference scramble + proj GEMM.
// As[s_local][c] = sum_q(Pq)/sum_q(Lq) at flat att index f = c*6400+(s0+sl)
// (the transpose/reshape scramble). Coalesced Pb reads; weights cast in-reg.
// grid (200, 2), block 256.
// ---------------------------------------------------------------------------
__global__ __launch_bounds__(256) void proj_comb(
    const unsigned short* __restrict__ Pb, const float* __restrict__ Lsum,
    const float* __restrict__ p_w, const float* __restrict__ p_b,
    float* __restrict__ Out, int nsplit)
{
  __shared__ unsigned short As[32][136];
  int t = threadIdx.x;
  int b = blockIdx.y;
  int s0 = blockIdx.x * 32;

  {
    int tx = t & 31, cg = t >> 5;          // lane sweeps s (coalesced in f)
#pragma unroll
    for (int it = 0; it < 16; ++it) {
      int c = cg * 16 + it;
      int f = c * NQ + s0 + tx;            // flat att index = n*128 + h*16+d
      int n = f >> 7, hh = (f >> 4) & 7;
      float ps = 0.f, L = 0.f;
      for (int qq = 0; qq < nsplit; ++qq) {
        int sl2 = qq * 2 + b;
        ps += __uint_as_float((unsigned)Pb[(size_t)sl2 * (NQ * DIM) + f] << 16);
        L += Lsum[(size_t)sl2 * (HEADS * NQ) + (size_t)hh * NQ + n];
      }
      As[tx][c] = f2bf(ps / L);
    }
  }
  __syncthreads();

  int ln = t & 31, hf = (t >> 5) & 1, wid = t >> 6;
  int o = wid * 32 + ln;
  const float* brow = p_w + (size_t)o * DIM + hf * 8;
  const unsigned short* arow = &As[ln][hf * 8];
  f32x16 acc = {};
#pragma unroll
  for (int c0 = 0; c0 < 128; c0 += 16) {
    bf16x8 af = *(const bf16x8*)&arow[c0];
    acc = __builtin_amdgcn_mfma_f32_32x32x16_bf16(af, ldw8(&brow[c0]), acc, 0, 0, 0);
  }
  float bv = p_b[o];
  float* obase = &Out[((size_t)b * DIM + o) * NQ + s0 + 4 * hf];
#pragma unroll
  for (int g = 0; g < 4; ++g) {
    float4 r;
    r.x = acc[4 * g + 0] + bv; r.y = acc[4 * g + 1] + bv;
    r.z = acc[4 * g + 2] + bv; r.w = acc[4 * g + 3] + bv;
    *(float4*)&obase[8 * g] = r;
  }
}

// ---------------------------------------------------------------------------
extern "C" void kernel_launch(void* const* d_in, const int* in_sizes, int n_in,
                              void* d_out, int out_size, void* d_ws, size_t ws_size,
                              hipStream_t stream)
{
  const float* x    = (const float*)d_in[0];
  const float* q_w  = (const float*)d_in[1];
  const float* q_b  = (const float*)d_in[2];
  const float* k_w  = (const float*)d_in[3];
  const float* k_b  = (const float*)d_in[4];
  const float* v_w  = (const float*)d_in[5];
  const float* v_b  = (const float*)d_in[6];
  const float* sr_w = (const float*)d_in[7];
  const float* sr_b = (const float*)d_in[8];
  const float* bng  = (const float*)d_in[9];
  const float* bnb  = (const float*)d_in[10];
  const float* bnm  = (const float*)d_in[11];
  const float* bnv  = (const float*)d_in[12];
  const float* p_w  = (const float*)d_in[13];
  const float* p_b  = (const float*)d_in[14];
  float* out = (float*)d_out;

  // kv-split: 4 if workspace allows (20.48 MB), else 2 (13.1 MB). ws_size is
  // constant per session -> identical behavior every call (graph-safe).
  const int nsplit = (ws_size >= (size_t)5120000 * 4) ? 4 : 2;

  float* ws = (float*)d_ws;
  // f32-slot layout (bf16 buffers use 2 elems/slot):
  //   Pb   [0, nsplit*819200)  -- attn partials (2*nsplit slices of NQ*128 bf16)
  //        xkvb nested at [0, 204800): dead before attn writes Pb.
  //   Qb, Kp, Vp, Lsum follow.
  bf16_t* Pb   = (bf16_t*)ws;
  bf16_t* xkvb = (bf16_t*)ws;
  size_t off = (size_t)nsplit * 819200;
  bf16_t* Qb = (bf16_t*)(ws + off);   off += 819200;
  bf16_t* Kp = (bf16_t*)(ws + off);   off += 204800;
  bf16_t* Vp = (bf16_t*)(ws + off);   off += 409600;
  float* Lsum = ws + off;             // 2*nsplit*HEADS*NQ f32

  const float sl = 0.25f * LOG2E;  // SCALE * log2(e) folded into Q

  // 1. q (blocks 0-199) + sr conv/BN/ReLU (blocks 200-249), direct from x
  mgemm_qsr<<<dim3(250, NBATCH), dim3(256), 0, stream>>>(
      x, q_w, q_b, sr_w, sr_b, bng, bnb, bnm, bnv,
      (unsigned short*)Qb, (unsigned short*)xkvb, sl);

  // 2. k (z=0) + v (z=1), fragment-major epilogues + denom fill
  mgemm_kv<<<dim3(NKV / 32, NBATCH, 2), dim3(256), 0, stream>>>(
      xkvb, k_w, k_b, v_w, v_b, (unsigned short*)Kp, (unsigned short*)Vp);

  // 3. attention partials (kv-split = nsplit)
  attn_split<<<dim3(NQ / 128, HEADS, 2 * nsplit), dim3(256), 0, stream>>>(
      Qb, Kp, Vp, (unsigned short*)Pb, Lsum, nsplit);

  // 4. combine + scramble + proj -> f32 chan-major final output (B,128,80,80)
  proj_comb<<<dim3(200, NBATCH), dim3(256), 0, stream>>>(
      (const unsigned short*)Pb, Lsum, p_w, p_b, out, nsplit);
}